// Round 2
// baseline (1102.434 us; speedup 1.0000x reference)
//
#include <hip/hip_runtime.h>
#include <hip/hip_bf16.h>
#include <math.h>

// Problem constants (from reference setup_inputs)
#define B_    8
#define C_    384
#define NH    8
#define HD    48
#define HW_   56
#define NPIX  3136      // 56*56
#define QKV3  1152      // 3*C
#define NS_   9

// ---------------------------------------------------------------------------
// Offsets: off[b,h,n,j] = sum_c x[b, h*48+c, n] * Woff[j, c]   (j in [0,18))
// One thread per (b,h,n). Coalesced over n for each c.
// ---------------------------------------------------------------------------
__global__ __launch_bounds__(256) void off_kernel(const float* __restrict__ x,
                                                  const float* __restrict__ Woff,
                                                  float* __restrict__ off) {
    __shared__ float Ws[18 * 48];
    for (int i = threadIdx.x; i < 18 * 48; i += 256) Ws[i] = Woff[i];
    __syncthreads();
    int gid = blockIdx.x * 256 + threadIdx.x;     // B*NH*NPIX = 200704
    int n  = gid % NPIX;
    int bh = gid / NPIX;
    int h  = bh & 7;
    int b  = bh >> 3;
    const float* xp = x + ((size_t)(b * C_ + h * HD)) * NPIX + n;
    float acc[18];
#pragma unroll
    for (int j = 0; j < 18; ++j) acc[j] = 0.f;
    for (int c = 0; c < HD; ++c) {
        float xv = xp[(size_t)c * NPIX];
#pragma unroll
        for (int j = 0; j < 18; ++j) acc[j] += xv * Ws[j * 48 + c];
    }
    float* op = off + (size_t)gid * 18;
#pragma unroll
    for (int j = 0; j < 18; ++j) op[j] = acc[j];
}

// ---------------------------------------------------------------------------
// QKV GEMM: qkv[(b*N+n)*1152 + j] = sum_c x[b,c,n] * Wqkv[j,c]
// A is K-major (x viewed as (B,C,N)).  BM=64(n) x BN=128(j) x BK=16, 256 thr,
// micro 4x8 per thread (j split tx*4 / 64+tx*4 to keep LDS reads 2-way).
// ---------------------------------------------------------------------------
__global__ __launch_bounds__(256) void qkv_gemm(const float* __restrict__ x,
                                                const float* __restrict__ Wqkv,
                                                float* __restrict__ qkv) {
    const int b  = blockIdx.z;
    const int n0 = blockIdx.y * 64;
    const int j0 = blockIdx.x * 128;
    __shared__ float As[16][64];
    __shared__ float Bs[16][132];   // padded: scatter writes 2-way, not 4-way
    const int tid = threadIdx.x;
    const int tx = tid & 15;        // j
    const int ty = tid >> 4;        // n
    float acc[4][8];
#pragma unroll
    for (int r = 0; r < 4; ++r)
#pragma unroll
        for (int u = 0; u < 8; ++u) acc[r][u] = 0.f;

    const float* xb = x + (size_t)b * C_ * NPIX + n0;
    const int ar = tid >> 4;              // k-row 0..15
    const int ac = (tid & 15) * 4;        // n-col
    const int jj = tid >> 2;              // 0..63
    const int cc = (tid & 3) * 4;         // k offset

    for (int k0 = 0; k0 < C_; k0 += 16) {
        float4 av  = *(const float4*)(xb + (size_t)(k0 + ar) * NPIX + ac);
        float4 bv0 = *(const float4*)(Wqkv + (size_t)(j0 + jj) * C_ + k0 + cc);
        float4 bv1 = *(const float4*)(Wqkv + (size_t)(j0 + 64 + jj) * C_ + k0 + cc);
        __syncthreads();
        *(float4*)&As[ar][ac] = av;
        Bs[cc + 0][jj] = bv0.x; Bs[cc + 1][jj] = bv0.y;
        Bs[cc + 2][jj] = bv0.z; Bs[cc + 3][jj] = bv0.w;
        Bs[cc + 0][64 + jj] = bv1.x; Bs[cc + 1][64 + jj] = bv1.y;
        Bs[cc + 2][64 + jj] = bv1.z; Bs[cc + 3][64 + jj] = bv1.w;
        __syncthreads();
#pragma unroll
        for (int kk = 0; kk < 16; ++kk) {
            float4 a  = *(const float4*)&As[kk][ty * 4];
            float4 b0 = *(const float4*)&Bs[kk][tx * 4];
            float4 b1 = *(const float4*)&Bs[kk][64 + tx * 4];
            float aa[4] = {a.x, a.y, a.z, a.w};
            float bb[8] = {b0.x, b0.y, b0.z, b0.w, b1.x, b1.y, b1.z, b1.w};
#pragma unroll
            for (int r = 0; r < 4; ++r)
#pragma unroll
                for (int u = 0; u < 8; ++u) acc[r][u] += aa[r] * bb[u];
        }
    }
    float* op = qkv + ((size_t)b * NPIX + n0 + ty * 4) * QKV3 + j0 + tx * 4;
#pragma unroll
    for (int r = 0; r < 4; ++r) {
        float4 v0 = {acc[r][0], acc[r][1], acc[r][2], acc[r][3]};
        float4 v1 = {acc[r][4], acc[r][5], acc[r][6], acc[r][7]};
        *(float4*)(op + (size_t)r * QKV3)      = v0;
        *(float4*)(op + (size_t)r * QKV3 + 64) = v1;
    }
}

// ---------------------------------------------------------------------------
// Fused deformable attention (online softmax). One thread per (b,h,n).
// ---------------------------------------------------------------------------
__global__ __launch_bounds__(256) void attn_kernel(const float* __restrict__ qkv,
                                                   const float* __restrict__ off,
                                                   float* __restrict__ attn_out) {
    const int gid = blockIdx.x * 256 + threadIdx.x;   // B*NH*NPIX
    const int n  = gid % NPIX;
    const int bh = gid / NPIX;
    const int h  = bh & 7;
    const int b  = bh >> 3;
    const int iy = n / HW_;
    const int ix = n % HW_;
    const float* base = qkv + (size_t)b * NPIX * QKV3;
    const float* qp = base + (size_t)n * QKV3 + h * HD;
    float4 q[12];
#pragma unroll
    for (int i = 0; i < 12; ++i) q[i] = *(const float4*)(qp + i * 4);
    const float* offp = off + (size_t)gid * 18;
    const float* kb = base + C_ + h * HD;       // k section
    const float* vb = base + 2 * C_ + h * HD;   // v section
    const float scale = 0.14433756729740643f;   // 48^-0.5

    float m = -INFINITY, ssum = 0.f;
    float4 o[12];
#pragma unroll
    for (int i = 0; i < 12; ++i) o[i] = make_float4(0.f, 0.f, 0.f, 0.f);

    for (int t = 0; t < 9; ++t) {
        float ys = (float)iy + (float)(t / 3 - 1) + offp[2 * t];
        float xs = (float)ix + (float)(t % 3 - 1) + offp[2 * t + 1];
        float y0f = floorf(ys), x0f = floorf(xs);
        float wy = ys - y0f, wx = xs - x0f;
        int y0 = (int)y0f, x0 = (int)x0f;
        int y1 = y0 + 1,  x1 = x0 + 1;
        float vy0 = (y0 >= 0 && y0 < HW_) ? 1.f : 0.f;
        float vy1 = (y1 >= 0 && y1 < HW_) ? 1.f : 0.f;
        float vx0 = (x0 >= 0 && x0 < HW_) ? 1.f : 0.f;
        float vx1 = (x1 >= 0 && x1 < HW_) ? 1.f : 0.f;
        float w00 = (1.f - wy) * (1.f - wx) * vy0 * vx0;
        float w01 = (1.f - wy) * wx * vy0 * vx1;
        float w10 = wy * (1.f - wx) * vy1 * vx0;
        float w11 = wy * wx * vy1 * vx1;
        int y0c = min(max(y0, 0), HW_ - 1), y1c = min(max(y1, 0), HW_ - 1);
        int x0c = min(max(x0, 0), HW_ - 1), x1c = min(max(x1, 0), HW_ - 1);
        int i00 = (y0c * HW_ + x0c) * QKV3;
        int i01 = (y0c * HW_ + x1c) * QKV3;
        int i10 = (y1c * HW_ + x0c) * QKV3;
        int i11 = (y1c * HW_ + x1c) * QKV3;

        float a = 0.f;
#pragma unroll
        for (int c = 0; c < 12; ++c) {
            float4 k00 = *(const float4*)(kb + i00 + c * 4);
            float4 k01 = *(const float4*)(kb + i01 + c * 4);
            float4 k10 = *(const float4*)(kb + i10 + c * 4);
            float4 k11 = *(const float4*)(kb + i11 + c * 4);
            float sx = w00 * k00.x + w01 * k01.x + w10 * k10.x + w11 * k11.x;
            float sy = w00 * k00.y + w01 * k01.y + w10 * k10.y + w11 * k11.y;
            float sz = w00 * k00.z + w01 * k01.z + w10 * k10.z + w11 * k11.z;
            float sw = w00 * k00.w + w01 * k01.w + w10 * k10.w + w11 * k11.w;
            a += q[c].x * sx + q[c].y * sy + q[c].z * sz + q[c].w * sw;
        }
        a *= scale;
        float mnew = fmaxf(m, a);
        float corr = __expf(m - mnew);     // 0 on first tap (m = -inf)
        float p    = __expf(a - mnew);
        ssum = ssum * corr + p;
#pragma unroll
        for (int c = 0; c < 12; ++c) {
            float4 v00 = *(const float4*)(vb + i00 + c * 4);
            float4 v01 = *(const float4*)(vb + i01 + c * 4);
            float4 v10 = *(const float4*)(vb + i10 + c * 4);
            float4 v11 = *(const float4*)(vb + i11 + c * 4);
            float sx = w00 * v00.x + w01 * v01.x + w10 * v10.x + w11 * v11.x;
            float sy = w00 * v00.y + w01 * v01.y + w10 * v10.y + w11 * v11.y;
            float sz = w00 * v00.z + w01 * v01.z + w10 * v10.z + w11 * v11.z;
            float sw = w00 * v00.w + w01 * v01.w + w10 * v10.w + w11 * v11.w;
            o[c].x = o[c].x * corr + p * sx;
            o[c].y = o[c].y * corr + p * sy;
            o[c].z = o[c].z * corr + p * sz;
            o[c].w = o[c].w * corr + p * sw;
        }
        m = mnew;
    }
    float inv = 1.f / ssum;
    float* op2 = attn_out + ((size_t)(b * NPIX + n)) * C_ + h * HD;
#pragma unroll
    for (int c = 0; c < 12; ++c) {
        float4 v = {o[c].x * inv, o[c].y * inv, o[c].z * inv, o[c].w * inv};
        *(float4*)(op2 + c * 4) = v;
    }
}

// ---------------------------------------------------------------------------
// Proj GEMM + bias + transposed store:
// out[(b*C + j)*N + n] = sum_c A[(b*N+n)*C + c] * Wp[j*C + c] + bias[j]
// BM=64(n) x BN=128(j) x BK=16; tx->n (coalesced store), ty->j (split).
// ---------------------------------------------------------------------------
__global__ __launch_bounds__(256) void proj_gemm(const float* __restrict__ A,
                                                 const float* __restrict__ Wp,
                                                 const float* __restrict__ bias,
                                                 float* __restrict__ out) {
    const int mt = blockIdx.y;            // 0..391
    const int b  = mt / 49;
    const int n0 = (mt % 49) * 64;
    const int j0 = blockIdx.x * 128;
    __shared__ float As[16][68];          // padded scatter
    __shared__ float Bs[16][132];
    const int tid = threadIdx.x;
    const int tx = tid & 15;              // n: 4 vals
    const int ty = tid >> 4;              // j: 8 vals (split)
    float acc[8][4];
#pragma unroll
    for (int r = 0; r < 8; ++r)
#pragma unroll
        for (int s = 0; s < 4; ++s) acc[r][s] = 0.f;

    const float* Ab = A + ((size_t)b * NPIX + n0) * C_;
    const int amm  = tid >> 2;            // 0..63 (n)
    const int ac4  = (tid & 3) * 4;       // k
    const int jj   = tid >> 2;
    const int cc   = (tid & 3) * 4;

    for (int k0 = 0; k0 < C_; k0 += 16) {
        float4 av  = *(const float4*)(Ab + (size_t)amm * C_ + k0 + ac4);
        float4 bv0 = *(const float4*)(Wp + (size_t)(j0 + jj) * C_ + k0 + cc);
        float4 bv1 = *(const float4*)(Wp + (size_t)(j0 + 64 + jj) * C_ + k0 + cc);
        __syncthreads();
        As[ac4 + 0][amm] = av.x; As[ac4 + 1][amm] = av.y;
        As[ac4 + 2][amm] = av.z; As[ac4 + 3][amm] = av.w;
        Bs[cc + 0][jj] = bv0.x; Bs[cc + 1][jj] = bv0.y;
        Bs[cc + 2][jj] = bv0.z; Bs[cc + 3][jj] = bv0.w;
        Bs[cc + 0][64 + jj] = bv1.x; Bs[cc + 1][64 + jj] = bv1.y;
        Bs[cc + 2][64 + jj] = bv1.z; Bs[cc + 3][64 + jj] = bv1.w;
        __syncthreads();
#pragma unroll
        for (int kk = 0; kk < 16; ++kk) {
            float4 a  = *(const float4*)&As[kk][tx * 4];
            float4 b0 = *(const float4*)&Bs[kk][ty * 4];
            float4 b1 = *(const float4*)&Bs[kk][64 + ty * 4];
            float aa[4] = {a.x, a.y, a.z, a.w};
            float bb[8] = {b0.x, b0.y, b0.z, b0.w, b1.x, b1.y, b1.z, b1.w};
#pragma unroll
            for (int r = 0; r < 8; ++r)
#pragma unroll
                for (int s = 0; s < 4; ++s) acc[r][s] += bb[r] * aa[s];
        }
    }
#pragma unroll
    for (int g = 0; g < 2; ++g)
#pragma unroll
        for (int r = 0; r < 4; ++r) {
            int j = j0 + g * 64 + ty * 4 + r;
            float bj = bias[j];
            float4 v = {acc[g * 4 + r][0] + bj, acc[g * 4 + r][1] + bj,
                        acc[g * 4 + r][2] + bj, acc[g * 4 + r][3] + bj};
            *(float4*)(out + ((size_t)b * C_ + j) * NPIX + n0 + tx * 4) = v;
        }
}

// ---------------------------------------------------------------------------
extern "C" void kernel_launch(void* const* d_in, const int* in_sizes, int n_in,
                              void* d_out, int out_size, void* d_ws, size_t ws_size,
                              hipStream_t stream) {
    const float* x     = (const float*)d_in[0];
    const float* Wqkv  = (const float*)d_in[1];
    const float* Woff  = (const float*)d_in[2];
    const float* Wproj = (const float*)d_in[3];
    const float* bproj = (const float*)d_in[4];
    float* out = (float*)d_out;

    // workspace layout (floats): qkv 28,901,376 | off 3,612,672 | attn 9,633,792
    // total 168.6 MB
    float* qkv      = (float*)d_ws;
    float* off      = qkv + (size_t)B_ * NPIX * QKV3;
    float* attn_out = off + (size_t)B_ * NH * NPIX * 18;

    off_kernel<<<(B_ * NH * NPIX) / 256, 256, 0, stream>>>(x, Woff, off);
    qkv_gemm<<<dim3(QKV3 / 128, NPIX / 64, B_), 256, 0, stream>>>(x, Wqkv, qkv);
    attn_kernel<<<(B_ * NH * NPIX) / 256, 256, 0, stream>>>(qkv, off, attn_out);
    proj_gemm<<<dim3(C_ / 128, (B_ * NPIX) / 64), 256, 0, stream>>>(attn_out, Wproj, bproj, out);
}

// Round 3
// 807.223 us; speedup vs baseline: 1.3657x; 1.3657x over previous
//
#include <hip/hip_runtime.h>
#include <hip/hip_bf16.h>
#include <math.h>

// Problem constants (from reference setup_inputs)
#define B_    8
#define C_    384
#define NH    8
#define HD    48
#define HW_   56
#define NPIX  3136      // 56*56
#define QKV3  1152      // 3*C
#define PLANE ((size_t)B_ * NH * NPIX * HD)   // 9,633,792 floats per q/k/v plane

// ---------------------------------------------------------------------------
// Offsets: off[bh][n][j] = sum_c x[b, h*48+c, n] * Woff[j, c]   (j in [0,18))
// ---------------------------------------------------------------------------
__global__ __launch_bounds__(256) void off_kernel(const float* __restrict__ x,
                                                  const float* __restrict__ Woff,
                                                  float* __restrict__ off) {
    __shared__ float Ws[18 * 48];
    for (int i = threadIdx.x; i < 18 * 48; i += 256) Ws[i] = Woff[i];
    __syncthreads();
    int gid = blockIdx.x * 256 + threadIdx.x;     // B*NH*NPIX = 200704
    int n  = gid % NPIX;
    int bh = gid / NPIX;
    int h  = bh & 7;
    int b  = bh >> 3;
    const float* xp = x + ((size_t)(b * C_ + h * HD)) * NPIX + n;
    float acc[18];
#pragma unroll
    for (int j = 0; j < 18; ++j) acc[j] = 0.f;
    for (int c = 0; c < HD; ++c) {
        float xv = xp[(size_t)c * NPIX];
#pragma unroll
        for (int j = 0; j < 18; ++j) acc[j] += xv * Ws[j * 48 + c];
    }
    float* op = off + (size_t)gid * 18;
#pragma unroll
    for (int j = 0; j < 18; ++j) op[j] = acc[j];
}

// ---------------------------------------------------------------------------
// QKV GEMM: computes sum_c x[b,c,n] * Wqkv[j,c], stores PLANAR per-head:
//   qkvp[s][b][h][n][d]  with j = s*384 + h*48 + d
// BM=64(n) x BN=128(j) x BK=16, 256 thr, micro 4x8.
// ---------------------------------------------------------------------------
__global__ __launch_bounds__(256) void qkv_gemm(const float* __restrict__ x,
                                                const float* __restrict__ Wqkv,
                                                float* __restrict__ qkvp) {
    const int b  = blockIdx.z;
    const int n0 = blockIdx.y * 64;
    const int j0 = blockIdx.x * 128;
    __shared__ float As[16][64];
    __shared__ float Bs[16][132];
    const int tid = threadIdx.x;
    const int tx = tid & 15;        // j
    const int ty = tid >> 4;        // n
    float acc[4][8];
#pragma unroll
    for (int r = 0; r < 4; ++r)
#pragma unroll
        for (int u = 0; u < 8; ++u) acc[r][u] = 0.f;

    const float* xb = x + (size_t)b * C_ * NPIX + n0;
    const int ar = tid >> 4;              // k-row 0..15
    const int ac = (tid & 15) * 4;        // n-col
    const int jj = tid >> 2;              // 0..63
    const int cc = (tid & 3) * 4;         // k offset

    for (int k0 = 0; k0 < C_; k0 += 16) {
        float4 av  = *(const float4*)(xb + (size_t)(k0 + ar) * NPIX + ac);
        float4 bv0 = *(const float4*)(Wqkv + (size_t)(j0 + jj) * C_ + k0 + cc);
        float4 bv1 = *(const float4*)(Wqkv + (size_t)(j0 + 64 + jj) * C_ + k0 + cc);
        __syncthreads();
        *(float4*)&As[ar][ac] = av;
        Bs[cc + 0][jj] = bv0.x; Bs[cc + 1][jj] = bv0.y;
        Bs[cc + 2][jj] = bv0.z; Bs[cc + 3][jj] = bv0.w;
        Bs[cc + 0][64 + jj] = bv1.x; Bs[cc + 1][64 + jj] = bv1.y;
        Bs[cc + 2][64 + jj] = bv1.z; Bs[cc + 3][64 + jj] = bv1.w;
        __syncthreads();
#pragma unroll
        for (int kk = 0; kk < 16; ++kk) {
            float4 a  = *(const float4*)&As[kk][ty * 4];
            float4 b0 = *(const float4*)&Bs[kk][tx * 4];
            float4 b1 = *(const float4*)&Bs[kk][64 + tx * 4];
            float aa[4] = {a.x, a.y, a.z, a.w};
            float bb[8] = {b0.x, b0.y, b0.z, b0.w, b1.x, b1.y, b1.z, b1.w};
#pragma unroll
            for (int r = 0; r < 4; ++r)
#pragma unroll
                for (int u = 0; u < 8; ++u) acc[r][u] += aa[r] * bb[u];
        }
    }
    // planar scatter epilogue: j -> (s,h,d); each float4 chunk stays in one head
    const int j1 = j0 + tx * 4;
    const int s1 = j1 / C_, r1 = j1 - s1 * C_;
    const int h1 = r1 / HD, d1 = r1 - h1 * HD;
    const int j2 = j1 + 64;
    const int s2 = j2 / C_, r2 = j2 - s2 * C_;
    const int h2 = r2 / HD, d2 = r2 - h2 * HD;
    float* p1 = qkvp + (size_t)s1 * PLANE + (size_t)(b * NH + h1) * NPIX * HD + d1;
    float* p2 = qkvp + (size_t)s2 * PLANE + (size_t)(b * NH + h2) * NPIX * HD + d2;
#pragma unroll
    for (int r = 0; r < 4; ++r) {
        const int n = n0 + ty * 4 + r;
        float4 v0 = {acc[r][0], acc[r][1], acc[r][2], acc[r][3]};
        float4 v1 = {acc[r][4], acc[r][5], acc[r][6], acc[r][7]};
        *(float4*)(p1 + (size_t)n * HD) = v0;
        *(float4*)(p2 + (size_t)n * HD) = v1;
    }
}

// ---------------------------------------------------------------------------
// Fused deformable attention, 4 lanes per pixel (12 channels each).
// Planar k/v gather (192B contiguous rows), XCD-aware block swizzle.
// ---------------------------------------------------------------------------
__device__ __forceinline__ float dot12(const float* __restrict__ p,
                                       float4 q0, float4 q1, float4 q2) {
    float4 a = *(const float4*)p;
    float4 b = *(const float4*)(p + 4);
    float4 c = *(const float4*)(p + 8);
    return q0.x * a.x + q0.y * a.y + q0.z * a.z + q0.w * a.w
         + q1.x * b.x + q1.y * b.y + q1.z * b.z + q1.w * b.w
         + q2.x * c.x + q2.y * c.y + q2.z * c.z + q2.w * c.w;
}

__device__ __forceinline__ void acc12(const float* __restrict__ p, float w,
                                      float4& s0, float4& s1, float4& s2) {
    float4 a = *(const float4*)p;
    float4 b = *(const float4*)(p + 4);
    float4 c = *(const float4*)(p + 8);
    s0.x += w * a.x; s0.y += w * a.y; s0.z += w * a.z; s0.w += w * a.w;
    s1.x += w * b.x; s1.y += w * b.y; s1.z += w * b.z; s1.w += w * b.w;
    s2.x += w * c.x; s2.y += w * c.y; s2.z += w * c.z; s2.w += w * c.w;
}

__global__ __launch_bounds__(256) void attn_kernel(const float* __restrict__ qkvp,
                                                   const float* __restrict__ off,
                                                   float* __restrict__ attn_out) {
    // XCD swizzle: 3136 blocks, consecutive blockIdx round-robin XCDs (%8).
    // Give each XCD 8 complete (b,h) slices -> k/v slice (1.2 MB) stays in its L2.
    const int blk  = blockIdx.x;
    const int xcd  = blk & 7;
    const int idx  = blk >> 3;            // 0..391
    const int grp  = idx / 49;            // 0..7
    const int tile = idx - grp * 49;      // 0..48
    const int bh   = xcd + (grp << 3);    // 0..63
    const int h = bh & 7, b = bh >> 3;
    const int s4 = threadIdx.x & 3;       // channel quarter (12 ch)
    const int n  = tile * 64 + (threadIdx.x >> 2);
    const int iy = n / HW_, ix = n % HW_;

    const float* qb = qkvp + (size_t)bh * NPIX * HD;   // b*NH+h == bh
    const float* kb = qb + PLANE;
    const float* vb = qb + 2 * PLANE;

    float4 q0, q1, q2;
    {
        const float* qp = qb + (size_t)n * HD + s4 * 12;
        q0 = *(const float4*)(qp);
        q1 = *(const float4*)(qp + 4);
        q2 = *(const float4*)(qp + 8);
    }
    const float* offp = off + ((size_t)bh * NPIX + n) * 18;
    const float scale = 0.14433756729740643f;   // 48^-0.5

    float m = -INFINITY, ssum = 0.f;
    float4 o0 = make_float4(0.f, 0.f, 0.f, 0.f);
    float4 o1 = o0, o2 = o0;

    for (int t = 0; t < 9; ++t) {
        float ys = (float)(iy + (t / 3) - 1) + offp[2 * t];
        float xs = (float)(ix + (t % 3) - 1) + offp[2 * t + 1];
        float y0f = floorf(ys), x0f = floorf(xs);
        float wy = ys - y0f, wx = xs - x0f;
        int y0 = (int)y0f, x0 = (int)x0f;
        int y1 = y0 + 1,  x1 = x0 + 1;
        float vy0 = (y0 >= 0 && y0 < HW_) ? 1.f : 0.f;
        float vy1 = (y1 >= 0 && y1 < HW_) ? 1.f : 0.f;
        float vx0 = (x0 >= 0 && x0 < HW_) ? 1.f : 0.f;
        float vx1 = (x1 >= 0 && x1 < HW_) ? 1.f : 0.f;
        float w00 = (1.f - wy) * (1.f - wx) * vy0 * vx0;
        float w01 = (1.f - wy) * wx * vy0 * vx1;
        float w10 = wy * (1.f - wx) * vy1 * vx0;
        float w11 = wy * wx * vy1 * vx1;
        int y0c = min(max(y0, 0), HW_ - 1), y1c = min(max(y1, 0), HW_ - 1);
        int x0c = min(max(x0, 0), HW_ - 1), x1c = min(max(x1, 0), HW_ - 1);
        int i00 = (y0c * HW_ + x0c) * HD + s4 * 12;
        int i01 = (y0c * HW_ + x1c) * HD + s4 * 12;
        int i10 = (y1c * HW_ + x0c) * HD + s4 * 12;
        int i11 = (y1c * HW_ + x1c) * HD + s4 * 12;

        float a = w00 * dot12(kb + i00, q0, q1, q2)
                + w01 * dot12(kb + i01, q0, q1, q2)
                + w10 * dot12(kb + i10, q0, q1, q2)
                + w11 * dot12(kb + i11, q0, q1, q2);
        a += __shfl_xor(a, 1);     // sum partial dots across the 4-lane group
        a += __shfl_xor(a, 2);
        a *= scale;

        float mnew = fmaxf(m, a);
        float corr = __expf(m - mnew);     // 0 on first tap (m = -inf)
        float p    = __expf(a - mnew);
        ssum = ssum * corr + p;

        float4 s0 = make_float4(0.f, 0.f, 0.f, 0.f), s1 = s0, s2 = s0;
        acc12(vb + i00, w00, s0, s1, s2);
        acc12(vb + i01, w01, s0, s1, s2);
        acc12(vb + i10, w10, s0, s1, s2);
        acc12(vb + i11, w11, s0, s1, s2);
        o0.x = o0.x * corr + p * s0.x; o0.y = o0.y * corr + p * s0.y;
        o0.z = o0.z * corr + p * s0.z; o0.w = o0.w * corr + p * s0.w;
        o1.x = o1.x * corr + p * s1.x; o1.y = o1.y * corr + p * s1.y;
        o1.z = o1.z * corr + p * s1.z; o1.w = o1.w * corr + p * s1.w;
        o2.x = o2.x * corr + p * s2.x; o2.y = o2.y * corr + p * s2.y;
        o2.z = o2.z * corr + p * s2.z; o2.w = o2.w * corr + p * s2.w;
        m = mnew;
    }
    float inv = 1.f / ssum;
    float* op2 = attn_out + ((size_t)(b * NPIX + n)) * C_ + h * HD + s4 * 12;
    float4 r0 = {o0.x * inv, o0.y * inv, o0.z * inv, o0.w * inv};
    float4 r1 = {o1.x * inv, o1.y * inv, o1.z * inv, o1.w * inv};
    float4 r2 = {o2.x * inv, o2.y * inv, o2.z * inv, o2.w * inv};
    *(float4*)(op2)     = r0;
    *(float4*)(op2 + 4) = r1;
    *(float4*)(op2 + 8) = r2;
}

// ---------------------------------------------------------------------------
// Proj GEMM + bias + transposed store:
// out[(b*C + j)*N + n] = sum_c A[(b*N+n)*C + c] * Wp[j*C + c] + bias[j]
// ---------------------------------------------------------------------------
__global__ __launch_bounds__(256) void proj_gemm(const float* __restrict__ A,
                                                 const float* __restrict__ Wp,
                                                 const float* __restrict__ bias,
                                                 float* __restrict__ out) {
    const int mt = blockIdx.y;            // 0..391
    const int b  = mt / 49;
    const int n0 = (mt % 49) * 64;
    const int j0 = blockIdx.x * 128;
    __shared__ float As[16][68];
    __shared__ float Bs[16][132];
    const int tid = threadIdx.x;
    const int tx = tid & 15;              // n: 4 vals
    const int ty = tid >> 4;              // j: 8 vals (split)
    float acc[8][4];
#pragma unroll
    for (int r = 0; r < 8; ++r)
#pragma unroll
        for (int s = 0; s < 4; ++s) acc[r][s] = 0.f;

    const float* Ab = A + ((size_t)b * NPIX + n0) * C_;
    const int amm  = tid >> 2;            // 0..63 (n)
    const int ac4  = (tid & 3) * 4;       // k
    const int jj   = tid >> 2;
    const int cc   = (tid & 3) * 4;

    for (int k0 = 0; k0 < C_; k0 += 16) {
        float4 av  = *(const float4*)(Ab + (size_t)amm * C_ + k0 + ac4);
        float4 bv0 = *(const float4*)(Wp + (size_t)(j0 + jj) * C_ + k0 + cc);
        float4 bv1 = *(const float4*)(Wp + (size_t)(j0 + 64 + jj) * C_ + k0 + cc);
        __syncthreads();
        As[ac4 + 0][amm] = av.x; As[ac4 + 1][amm] = av.y;
        As[ac4 + 2][amm] = av.z; As[ac4 + 3][amm] = av.w;
        Bs[cc + 0][jj] = bv0.x; Bs[cc + 1][jj] = bv0.y;
        Bs[cc + 2][jj] = bv0.z; Bs[cc + 3][jj] = bv0.w;
        Bs[cc + 0][64 + jj] = bv1.x; Bs[cc + 1][64 + jj] = bv1.y;
        Bs[cc + 2][64 + jj] = bv1.z; Bs[cc + 3][64 + jj] = bv1.w;
        __syncthreads();
#pragma unroll
        for (int kk = 0; kk < 16; ++kk) {
            float4 a  = *(const float4*)&As[kk][tx * 4];
            float4 b0 = *(const float4*)&Bs[kk][ty * 4];
            float4 b1 = *(const float4*)&Bs[kk][64 + ty * 4];
            float aa[4] = {a.x, a.y, a.z, a.w};
            float bb[8] = {b0.x, b0.y, b0.z, b0.w, b1.x, b1.y, b1.z, b1.w};
#pragma unroll
            for (int r = 0; r < 8; ++r)
#pragma unroll
                for (int s = 0; s < 4; ++s) acc[r][s] += bb[r] * aa[s];
        }
    }
#pragma unroll
    for (int g = 0; g < 2; ++g)
#pragma unroll
        for (int r = 0; r < 4; ++r) {
            int j = j0 + g * 64 + ty * 4 + r;
            float bj = bias[j];
            float4 v = {acc[g * 4 + r][0] + bj, acc[g * 4 + r][1] + bj,
                        acc[g * 4 + r][2] + bj, acc[g * 4 + r][3] + bj};
            *(float4*)(out + ((size_t)b * C_ + j) * NPIX + n0 + tx * 4) = v;
        }
}

// ---------------------------------------------------------------------------
extern "C" void kernel_launch(void* const* d_in, const int* in_sizes, int n_in,
                              void* d_out, int out_size, void* d_ws, size_t ws_size,
                              hipStream_t stream) {
    const float* x     = (const float*)d_in[0];
    const float* Wqkv  = (const float*)d_in[1];
    const float* Woff  = (const float*)d_in[2];
    const float* Wproj = (const float*)d_in[3];
    const float* bproj = (const float*)d_in[4];
    float* out = (float*)d_out;

    // workspace (floats): qkvp 28,901,376 | off 3,612,672 | attn 9,633,792
    float* qkvp     = (float*)d_ws;
    float* off      = qkvp + 3 * PLANE;
    float* attn_out = off + (size_t)B_ * NH * NPIX * 18;

    off_kernel<<<(B_ * NH * NPIX) / 256, 256, 0, stream>>>(x, Woff, off);
    qkv_gemm<<<dim3(QKV3 / 128, NPIX / 64, B_), 256, 0, stream>>>(x, Wqkv, qkvp);
    attn_kernel<<<NPIX, 256, 0, stream>>>(qkvp, off, attn_out);
    proj_gemm<<<dim3(C_ / 128, (B_ * NPIX) / 64), 256, 0, stream>>>(attn_out, Wproj, bproj, out);
}

// Round 5
// 416.597 us; speedup vs baseline: 2.6463x; 1.9377x over previous
//
#include <hip/hip_runtime.h>
#include <hip/hip_bf16.h>
#include <math.h>

#define B_    8
#define C_    384
#define NH    8
#define HD    48
#define HW_   56
#define NPIX  3136      // 56*56
#define QKV3  1152      // 3*C
#define PLANE ((size_t)B_ * NH * NPIX * HD)   // 9,633,792 elems per q/k/v plane

typedef __attribute__((ext_vector_type(8))) short bf16x8;
typedef __attribute__((ext_vector_type(4))) float f32x4;

// ---- fp32 -> bf16 hi/lo split helpers (bit-level, RN) ----------------------
__device__ __forceinline__ ushort f2bf(float x) {
    unsigned u = __float_as_uint(x);
    unsigned r = (u + 0x7FFFu + ((u >> 16) & 1u)) >> 16;
    return (ushort)r;
}
__device__ __forceinline__ float bf2f(ushort h) {
    return __uint_as_float(((unsigned)h) << 16);
}

// ---------------------------------------------------------------------------
// Weight converter: row-major [n] fp32 -> hi/lo bf16 same layout
// ---------------------------------------------------------------------------
__global__ __launch_bounds__(256) void convert_w(const float* __restrict__ w,
                                                 ushort* __restrict__ hi,
                                                 ushort* __restrict__ lo, int nelem) {
    int i = blockIdx.x * 256 + threadIdx.x;
    if (i < nelem) {
        float x = w[i];
        ushort h = f2bf(x);
        hi[i] = h;
        lo[i] = f2bf(x - bf2f(h));
    }
}

// ---------------------------------------------------------------------------
// x[b][c][n] fp32 -> xT[(b*NPIX+n)][c] bf16 hi/lo (tiled transpose)
// grid: (ntile 49, ctile 6, b 8), 256 threads, tile 64c x 64n
// ---------------------------------------------------------------------------
__global__ __launch_bounds__(256) void convert_x(const float* __restrict__ x,
                                                 ushort* __restrict__ xh,
                                                 ushort* __restrict__ xl) {
    __shared__ float t[64][65];
    const int n0 = blockIdx.x * 64, c0 = blockIdx.y * 64, b = blockIdx.z;
    const int tid = threadIdx.x;
    const float* xb = x + ((size_t)b * C_ + c0) * NPIX + n0;
#pragma unroll
    for (int p = 0; p < 16; ++p) {
        int c = p * 4 + (tid >> 6);
        int n = tid & 63;
        t[c][n] = xb[(size_t)c * NPIX + n];
    }
    __syncthreads();
#pragma unroll
    for (int p = 0; p < 8; ++p) {
        int nr = p * 8 + (tid >> 5);
        int c2 = (tid & 31) * 2;
        float v0 = t[c2][nr], v1 = t[c2 + 1][nr];
        ushort h0 = f2bf(v0), h1 = f2bf(v1);
        ushort l0 = f2bf(v0 - bf2f(h0)), l1 = f2bf(v1 - bf2f(h1));
        size_t o = ((size_t)b * NPIX + n0 + nr) * C_ + c0 + c2;
        ushort2 hh; hh.x = h0; hh.y = h1;
        ushort2 ll; ll.x = l0; ll.y = l1;
        *(ushort2*)(xh + o) = hh;
        *(ushort2*)(xl + o) = ll;
    }
}

// ---------------------------------------------------------------------------
// Offsets: off[bh][n][j] = sum_c x[b, h*48+c, n] * Woff[j, c]
// ---------------------------------------------------------------------------
__global__ __launch_bounds__(256) void off_kernel(const float* __restrict__ x,
                                                  const float* __restrict__ Woff,
                                                  float* __restrict__ off) {
    __shared__ float Ws[18 * 48];
    for (int i = threadIdx.x; i < 18 * 48; i += 256) Ws[i] = Woff[i];
    __syncthreads();
    int gid = blockIdx.x * 256 + threadIdx.x;
    int n  = gid % NPIX;
    int bh = gid / NPIX;
    int h  = bh & 7;
    int b  = bh >> 3;
    const float* xp = x + ((size_t)(b * C_ + h * HD)) * NPIX + n;
    float acc[18];
#pragma unroll
    for (int j = 0; j < 18; ++j) acc[j] = 0.f;
    for (int c = 0; c < HD; ++c) {
        float xv = xp[(size_t)c * NPIX];
#pragma unroll
        for (int j = 0; j < 18; ++j) acc[j] += xv * Ws[j * 48 + c];
    }
    float* op = off + (size_t)gid * 18;
#pragma unroll
    for (int j = 0; j < 18; ++j) op[j] = acc[j];
}

// ---------------------------------------------------------------------------
// MFMA GEMM (bf16 hi/lo x4): D[m][j] = sum_k A[m][k]*B[j][k]
// A rows from `arows` (hi/lo, row-major stride 384), B rows from `brows`.
// Tile 128(m) x 128(j), BK=32, 4 waves (2x2), wave tile 64x64.
// LDS k-chunk-major [kc][row][8] -> conflict-free b128 reads/writes.
// QKV epilogue: planar scatter. (M = pixels m0=blockIdx.y*128, N = j)
// ---------------------------------------------------------------------------
__global__ __launch_bounds__(256) void qkv_mfma(const ushort* __restrict__ ah_g,
                                                const ushort* __restrict__ al_g,
                                                const ushort* __restrict__ bh_g,
                                                const ushort* __restrict__ bl_g,
                                                float* __restrict__ qkvp) {
    __shared__ alignas(16) ushort sm[16384];   // Ah | Al | Bh | Bl (4096 each)
    ushort* Ah = sm;
    ushort* Al = sm + 4096;
    ushort* Bh = sm + 8192;
    ushort* Bl = sm + 12288;
    const int tid = threadIdx.x;
    const int lane = tid & 63;
    const int wid = tid >> 6;
    const int wm = wid >> 1, wn = wid & 1;
    const int m0 = blockIdx.y * 128;
    const int j0 = blockIdx.x * 128;

    f32x4 acc[4][4];
#pragma unroll
    for (int i = 0; i < 4; ++i)
#pragma unroll
        for (int j = 0; j < 4; ++j) acc[i][j] = (f32x4){0.f, 0.f, 0.f, 0.f};

    const int kc0 = tid >> 7, r0 = tid & 127;   // slot tid
    const int kc1 = kc0 + 2;                    // slot tid+256 (same r0)
    const ushort* gA0h = ah_g + (size_t)(m0 + r0) * C_ + kc0 * 8;
    const ushort* gA1h = ah_g + (size_t)(m0 + r0) * C_ + kc1 * 8;
    const ushort* gA0l = al_g + (size_t)(m0 + r0) * C_ + kc0 * 8;
    const ushort* gA1l = al_g + (size_t)(m0 + r0) * C_ + kc1 * 8;
    const ushort* gB0h = bh_g + (size_t)(j0 + r0) * C_ + kc0 * 8;
    const ushort* gB1h = bh_g + (size_t)(j0 + r0) * C_ + kc1 * 8;
    const ushort* gB0l = bl_g + (size_t)(j0 + r0) * C_ + kc0 * 8;
    const ushort* gB1l = bl_g + (size_t)(j0 + r0) * C_ + kc1 * 8;
    const int s0 = tid * 8, s1 = (tid + 256) * 8;   // ushort offsets in each tile

    for (int k0 = 0; k0 < C_; k0 += 32) {
        uint4 vA0h = *(const uint4*)(gA0h + k0);
        uint4 vA1h = *(const uint4*)(gA1h + k0);
        uint4 vA0l = *(const uint4*)(gA0l + k0);
        uint4 vA1l = *(const uint4*)(gA1l + k0);
        uint4 vB0h = *(const uint4*)(gB0h + k0);
        uint4 vB1h = *(const uint4*)(gB1h + k0);
        uint4 vB0l = *(const uint4*)(gB0l + k0);
        uint4 vB1l = *(const uint4*)(gB1l + k0);
        __syncthreads();
        *(uint4*)(Ah + s0) = vA0h; *(uint4*)(Ah + s1) = vA1h;
        *(uint4*)(Al + s0) = vA0l; *(uint4*)(Al + s1) = vA1l;
        *(uint4*)(Bh + s0) = vB0h; *(uint4*)(Bh + s1) = vB1h;
        *(uint4*)(Bl + s0) = vB0l; *(uint4*)(Bl + s1) = vB1l;
        __syncthreads();

        bf16x8 fah[4], fal[4];
#pragma unroll
        for (int mf = 0; mf < 4; ++mf) {
            int row = wm * 64 + mf * 16 + (lane & 15);
            int idx = (((lane >> 4) << 7) + row) * 8;
            fah[mf] = *(const bf16x8*)(Ah + idx);
            fal[mf] = *(const bf16x8*)(Al + idx);
        }
#pragma unroll
        for (int nf = 0; nf < 4; ++nf) {
            int rowb = wn * 64 + nf * 16 + (lane & 15);
            int idxb = (((lane >> 4) << 7) + rowb) * 8;
            bf16x8 fbh = *(const bf16x8*)(Bh + idxb);
            bf16x8 fbl = *(const bf16x8*)(Bl + idxb);
#pragma unroll
            for (int mf = 0; mf < 4; ++mf) {
                acc[mf][nf] = __builtin_amdgcn_mfma_f32_16x16x32_bf16(fal[mf], fbl, acc[mf][nf], 0, 0, 0);
                acc[mf][nf] = __builtin_amdgcn_mfma_f32_16x16x32_bf16(fah[mf], fbl, acc[mf][nf], 0, 0, 0);
                acc[mf][nf] = __builtin_amdgcn_mfma_f32_16x16x32_bf16(fal[mf], fbh, acc[mf][nf], 0, 0, 0);
                acc[mf][nf] = __builtin_amdgcn_mfma_f32_16x16x32_bf16(fah[mf], fbh, acc[mf][nf], 0, 0, 0);
            }
        }
    }

    // planar scatter epilogue: j -> (s, head, d); m -> (b, n)
    size_t snf[4];
#pragma unroll
    for (int nf = 0; nf < 4; ++nf) {
        int j = j0 + wn * 64 + nf * 16 + (lane & 15);
        int s = j / C_; int rr = j - s * C_;
        int hh = rr / HD; int d = rr - hh * HD;
        snf[nf] = (size_t)s * PLANE + (size_t)hh * (NPIX * HD) + d;
    }
#pragma unroll
    for (int mf = 0; mf < 4; ++mf) {
#pragma unroll
        for (int reg = 0; reg < 4; ++reg) {
            int m = m0 + wm * 64 + mf * 16 + ((lane >> 4) << 2) + reg;
            int bb = m / NPIX; int n = m - bb * NPIX;
            size_t smr = (size_t)bb * (NH * NPIX * HD) + (size_t)n * HD;
#pragma unroll
            for (int nf = 0; nf < 4; ++nf)
                qkvp[snf[nf] + smr] = acc[mf][nf][reg];
        }
    }
}

// ---------------------------------------------------------------------------
// Proj MFMA: out[(b*C+j)*NPIX+n] = sum_c Wp[j][c]*attn[m=b*NPIX+n][c] + bias[j]
// A = Wproj rows (M=j, 3 tiles), B = attn planes rows (N=m, 196 tiles).
// ---------------------------------------------------------------------------
__global__ __launch_bounds__(256) void proj_mfma(const ushort* __restrict__ ah_g,
                                                 const ushort* __restrict__ al_g,
                                                 const ushort* __restrict__ bh_g,
                                                 const ushort* __restrict__ bl_g,
                                                 const float* __restrict__ bias,
                                                 float* __restrict__ out) {
    __shared__ alignas(16) ushort sm[16384];
    ushort* Ah = sm;
    ushort* Al = sm + 4096;
    ushort* Bh = sm + 8192;
    ushort* Bl = sm + 12288;
    const int tid = threadIdx.x;
    const int lane = tid & 63;
    const int wid = tid >> 6;
    const int wm = wid >> 1, wn = wid & 1;
    const int j0 = blockIdx.y * 128;
    const int n0 = blockIdx.x * 128;

    f32x4 acc[4][4];
#pragma unroll
    for (int i = 0; i < 4; ++i)
#pragma unroll
        for (int j = 0; j < 4; ++j) acc[i][j] = (f32x4){0.f, 0.f, 0.f, 0.f};

    const int kc0 = tid >> 7, r0 = tid & 127;
    const int kc1 = kc0 + 2;
    const ushort* gA0h = ah_g + (size_t)(j0 + r0) * C_ + kc0 * 8;
    const ushort* gA1h = ah_g + (size_t)(j0 + r0) * C_ + kc1 * 8;
    const ushort* gA0l = al_g + (size_t)(j0 + r0) * C_ + kc0 * 8;
    const ushort* gA1l = al_g + (size_t)(j0 + r0) * C_ + kc1 * 8;
    const ushort* gB0h = bh_g + (size_t)(n0 + r0) * C_ + kc0 * 8;
    const ushort* gB1h = bh_g + (size_t)(n0 + r0) * C_ + kc1 * 8;
    const ushort* gB0l = bl_g + (size_t)(n0 + r0) * C_ + kc0 * 8;
    const ushort* gB1l = bl_g + (size_t)(n0 + r0) * C_ + kc1 * 8;
    const int s0 = tid * 8, s1 = (tid + 256) * 8;

    for (int k0 = 0; k0 < C_; k0 += 32) {
        uint4 vA0h = *(const uint4*)(gA0h + k0);
        uint4 vA1h = *(const uint4*)(gA1h + k0);
        uint4 vA0l = *(const uint4*)(gA0l + k0);
        uint4 vA1l = *(const uint4*)(gA1l + k0);
        uint4 vB0h = *(const uint4*)(gB0h + k0);
        uint4 vB1h = *(const uint4*)(gB1h + k0);
        uint4 vB0l = *(const uint4*)(gB0l + k0);
        uint4 vB1l = *(const uint4*)(gB1l + k0);
        __syncthreads();
        *(uint4*)(Ah + s0) = vA0h; *(uint4*)(Ah + s1) = vA1h;
        *(uint4*)(Al + s0) = vA0l; *(uint4*)(Al + s1) = vA1l;
        *(uint4*)(Bh + s0) = vB0h; *(uint4*)(Bh + s1) = vB1h;
        *(uint4*)(Bl + s0) = vB0l; *(uint4*)(Bl + s1) = vB1l;
        __syncthreads();

        bf16x8 fah[4], fal[4];
#pragma unroll
        for (int mf = 0; mf < 4; ++mf) {
            int row = wm * 64 + mf * 16 + (lane & 15);
            int idx = (((lane >> 4) << 7) + row) * 8;
            fah[mf] = *(const bf16x8*)(Ah + idx);
            fal[mf] = *(const bf16x8*)(Al + idx);
        }
#pragma unroll
        for (int nf = 0; nf < 4; ++nf) {
            int rowb = wn * 64 + nf * 16 + (lane & 15);
            int idxb = (((lane >> 4) << 7) + rowb) * 8;
            bf16x8 fbh = *(const bf16x8*)(Bh + idxb);
            bf16x8 fbl = *(const bf16x8*)(Bl + idxb);
#pragma unroll
            for (int mf = 0; mf < 4; ++mf) {
                acc[mf][nf] = __builtin_amdgcn_mfma_f32_16x16x32_bf16(fal[mf], fbl, acc[mf][nf], 0, 0, 0);
                acc[mf][nf] = __builtin_amdgcn_mfma_f32_16x16x32_bf16(fah[mf], fbl, acc[mf][nf], 0, 0, 0);
                acc[mf][nf] = __builtin_amdgcn_mfma_f32_16x16x32_bf16(fal[mf], fbh, acc[mf][nf], 0, 0, 0);
                acc[mf][nf] = __builtin_amdgcn_mfma_f32_16x16x32_bf16(fah[mf], fbh, acc[mf][nf], 0, 0, 0);
            }
        }
    }

    // epilogue: rows = j (bias), cols = n (coalesced store)
    size_t obase[4];
#pragma unroll
    for (int nf = 0; nf < 4; ++nf) {
        int ncol = n0 + wn * 64 + nf * 16 + (lane & 15);
        int bb = ncol / NPIX; int n = ncol - bb * NPIX;
        obase[nf] = (size_t)bb * C_ * NPIX + n;
    }
#pragma unroll
    for (int mf = 0; mf < 4; ++mf) {
#pragma unroll
        for (int reg = 0; reg < 4; ++reg) {
            int j = j0 + wm * 64 + mf * 16 + ((lane >> 4) << 2) + reg;
            float bj = bias[j];
#pragma unroll
            for (int nf = 0; nf < 4; ++nf)
                out[obase[nf] + (size_t)j * NPIX] = acc[mf][nf][reg] + bj;
        }
    }
}

// ---------------------------------------------------------------------------
// Fused deformable attention: 4 lanes/pixel, three-phase, planar k/v gather,
// XCD-aware swizzle. Outputs bf16 hi/lo planes [b*NPIX+n][C] for proj MFMA.
// ---------------------------------------------------------------------------
__device__ __forceinline__ float dot12(const float* __restrict__ p,
                                       float4 q0, float4 q1, float4 q2) {
    float4 a = *(const float4*)p;
    float4 b = *(const float4*)(p + 4);
    float4 c = *(const float4*)(p + 8);
    return q0.x * a.x + q0.y * a.y + q0.z * a.z + q0.w * a.w
         + q1.x * b.x + q1.y * b.y + q1.z * b.z + q1.w * b.w
         + q2.x * c.x + q2.y * c.y + q2.z * c.z + q2.w * c.w;
}

__device__ __forceinline__ void acc12(const float* __restrict__ p, float w,
                                      float4& s0, float4& s1, float4& s2) {
    float4 a = *(const float4*)p;
    float4 b = *(const float4*)(p + 4);
    float4 c = *(const float4*)(p + 8);
    s0.x += w * a.x; s0.y += w * a.y; s0.z += w * a.z; s0.w += w * a.w;
    s1.x += w * b.x; s1.y += w * b.y; s1.z += w * b.z; s1.w += w * b.w;
    s2.x += w * c.x; s2.y += w * c.y; s2.z += w * c.z; s2.w += w * c.w;
}

__global__ __launch_bounds__(256) void attn_kernel(const float* __restrict__ qkvp,
                                                   const float* __restrict__ off,
                                                   ushort* __restrict__ at_hi,
                                                   ushort* __restrict__ at_lo) {
    const int blk  = blockIdx.x;
    const int xcd  = blk & 7;
    const int idx  = blk >> 3;
    const int grp  = idx / 49;
    const int tile = idx - grp * 49;
    const int bh   = xcd + (grp << 3);
    const int h = bh & 7, b = bh >> 3;
    const int s4 = threadIdx.x & 3;
    const int n  = tile * 64 + (threadIdx.x >> 2);
    const int iy = n / HW_, ix = n % HW_;

    const float* qb = qkvp + (size_t)bh * NPIX * HD;
    const float* kb = qb + PLANE;
    const float* vb = qb + 2 * PLANE;

    float4 q0, q1, q2;
    {
        const float* qp = qb + (size_t)n * HD + s4 * 12;
        q0 = *(const float4*)(qp);
        q1 = *(const float4*)(qp + 4);
        q2 = *(const float4*)(qp + 8);
    }
    const float* offp = off + ((size_t)bh * NPIX + n) * 18;
    const float scale = 0.14433756729740643f;

    float w0[9], w1[9], w2[9], w3[9];
    int   i0[9], i1[9], i2[9], i3[9];
#pragma unroll
    for (int t = 0; t < 9; ++t) {
        float ys = (float)(iy + (t / 3) - 1) + offp[2 * t];
        float xs = (float)(ix + (t % 3) - 1) + offp[2 * t + 1];
        float y0f = floorf(ys), x0f = floorf(xs);
        float wy = ys - y0f, wx = xs - x0f;
        int y0 = (int)y0f, x0 = (int)x0f;
        int y1 = y0 + 1,  x1 = x0 + 1;
        float vy0 = (y0 >= 0 && y0 < HW_) ? 1.f : 0.f;
        float vy1 = (y1 >= 0 && y1 < HW_) ? 1.f : 0.f;
        float vx0 = (x0 >= 0 && x0 < HW_) ? 1.f : 0.f;
        float vx1 = (x1 >= 0 && x1 < HW_) ? 1.f : 0.f;
        w0[t] = (1.f - wy) * (1.f - wx) * vy0 * vx0;
        w1[t] = (1.f - wy) * wx * vy0 * vx1;
        w2[t] = wy * (1.f - wx) * vy1 * vx0;
        w3[t] = wy * wx * vy1 * vx1;
        int y0c = min(max(y0, 0), HW_ - 1), y1c = min(max(y1, 0), HW_ - 1);
        int x0c = min(max(x0, 0), HW_ - 1), x1c = min(max(x1, 0), HW_ - 1);
        i0[t] = (y0c * HW_ + x0c) * HD + s4 * 12;
        i1[t] = (y0c * HW_ + x1c) * HD + s4 * 12;
        i2[t] = (y1c * HW_ + x0c) * HD + s4 * 12;
        i3[t] = (y1c * HW_ + x1c) * HD + s4 * 12;
    }

    float lg[9];
#pragma unroll
    for (int t = 0; t < 9; ++t) {
        lg[t] = w0[t] * dot12(kb + i0[t], q0, q1, q2)
              + w1[t] * dot12(kb + i1[t], q0, q1, q2)
              + w2[t] * dot12(kb + i2[t], q0, q1, q2)
              + w3[t] * dot12(kb + i3[t], q0, q1, q2);
    }
#pragma unroll
    for (int t = 0; t < 9; ++t) {
        lg[t] += __shfl_xor(lg[t], 1);
        lg[t] += __shfl_xor(lg[t], 2);
        lg[t] *= scale;
    }
    float mx = lg[0];
#pragma unroll
    for (int t = 1; t < 9; ++t) mx = fmaxf(mx, lg[t]);
    float p[9];
    float ssum = 0.f;
#pragma unroll
    for (int t = 0; t < 9; ++t) { p[t] = __expf(lg[t] - mx); ssum += p[t]; }
    const float inv = 1.f / ssum;

    float4 o0 = make_float4(0.f, 0.f, 0.f, 0.f);
    float4 o1 = o0, o2 = o0;
#pragma unroll
    for (int t = 0; t < 9; ++t) {
        acc12(vb + i0[t], p[t] * w0[t], o0, o1, o2);
        acc12(vb + i1[t], p[t] * w1[t], o0, o1, o2);
        acc12(vb + i2[t], p[t] * w2[t], o0, o1, o2);
        acc12(vb + i3[t], p[t] * w3[t], o0, o1, o2);
    }
    float vals[12] = {o0.x, o0.y, o0.z, o0.w, o1.x, o1.y, o1.z, o1.w,
                      o2.x, o2.y, o2.z, o2.w};
    ushort hs[12], ls[12];
#pragma unroll
    for (int i = 0; i < 12; ++i) {
        float v = vals[i] * inv;
        ushort hb = f2bf(v);
        hs[i] = hb;
        ls[i] = f2bf(v - bf2f(hb));
    }
    size_t orow = ((size_t)(b * NPIX + n)) * C_ + h * HD + s4 * 12;
#pragma unroll
    for (int i = 0; i < 3; ++i) {
        ushort4 a; a.x = hs[4 * i]; a.y = hs[4 * i + 1]; a.z = hs[4 * i + 2]; a.w = hs[4 * i + 3];
        ushort4 c; c.x = ls[4 * i]; c.y = ls[4 * i + 1]; c.z = ls[4 * i + 2]; c.w = ls[4 * i + 3];
        *(ushort4*)(at_hi + orow + 4 * i) = a;
        *(ushort4*)(at_lo + orow + 4 * i) = c;
    }
}

// ---------------------------------------------------------------------------
extern "C" void kernel_launch(void* const* d_in, const int* in_sizes, int n_in,
                              void* d_out, int out_size, void* d_ws, size_t ws_size,
                              hipStream_t stream) {
    const float* x     = (const float*)d_in[0];
    const float* Wqkv  = (const float*)d_in[1];
    const float* Woff  = (const float*)d_in[2];
    const float* Wproj = (const float*)d_in[3];
    const float* bproj = (const float*)d_in[4];
    float* out = (float*)d_out;

    // workspace layout (bytes), total ~171 MB:
    // qkvp fp32 115,605,504 | off fp32 14,450,688 | xT/attn hi+lo 38,535,168 |
    // wq hi+lo 1,769,472 | wp hi+lo 589,824
    char* w = (char*)d_ws;
    float*  qkvp  = (float*)w;
    float*  off   = (float*)(w + 115605504);
    ushort* xt_hi = (ushort*)(w + 115605504 + 14450688);
    ushort* xt_lo = xt_hi + 9633792;
    ushort* at_hi = xt_hi;                 // reuse: xT dead after qkv_mfma
    ushort* at_lo = xt_lo;
    ushort* wq_hi = xt_lo + 9633792;
    ushort* wq_lo = wq_hi + 442368;
    ushort* wp_hi = wq_lo + 442368;
    ushort* wp_lo = wp_hi + 147456;

    convert_w<<<1728, 256, 0, stream>>>(Wqkv, wq_hi, wq_lo, 442368);
    convert_w<<<576, 256, 0, stream>>>(Wproj, wp_hi, wp_lo, 147456);
    convert_x<<<dim3(49, 6, B_), 256, 0, stream>>>(x, xt_hi, xt_lo);
    off_kernel<<<(B_ * NH * NPIX) / 256, 256, 0, stream>>>(x, Woff, off);
    qkv_mfma<<<dim3(QKV3 / 128, (B_ * NPIX) / 128), 256, 0, stream>>>(
        xt_hi, xt_lo, wq_hi, wq_lo, qkvp);
    attn_kernel<<<NPIX, 256, 0, stream>>>(qkvp, off, at_hi, at_lo);
    proj_mfma<<<dim3((B_ * NPIX) / 128, C_ / 128), 256, 0, stream>>>(
        wp_hi, wp_lo, at_hi, at_lo, bproj, out);
}